// Round 11
// baseline (2129.190 us; speedup 1.0000x reference)
//
#include <hip/hip_runtime.h>
#include <cstdint>
#include <cstddef>

typedef __attribute__((ext_vector_type(8))) short short8;
typedef __attribute__((ext_vector_type(4))) float f32x4;
typedef __attribute__((ext_vector_type(4))) unsigned short us4;

#define N_SPK 64
#define M_UTT 10
#define T_SEQ 160
#define IN_F  40
#define H_DIM 256
#define B_TOT 640
#define G4    1024
#define FSTR  64   // flag stride in ints (256 B/flag: own cache line)

__device__ __forceinline__ unsigned short f2bf(float f) {
  unsigned int u = __float_as_uint(f);
  u += 0x7FFFu + ((u >> 16) & 1u);   // round-to-nearest-even
  return (unsigned short)(u >> 16);
}
__device__ __forceinline__ float b2f(unsigned short u) {
  return __uint_as_float(((unsigned int)u) << 16);
}
__device__ __forceinline__ float sigm(float x) {
  return 1.f / (1.f + __expf(-x));
}
__device__ __forceinline__ float tanh_fast(float x) {
  return 1.f - 2.f / (1.f + __expf(2.f * x));
}
__device__ __forceinline__ unsigned long long ato_ld(const unsigned long long* p) {
  return __hip_atomic_load(p, __ATOMIC_RELAXED, __HIP_MEMORY_SCOPE_AGENT);
}
__device__ __forceinline__ void ato_st(unsigned long long* p, unsigned long long v) {
  __hip_atomic_store(p, v, __ATOMIC_RELAXED, __HIP_MEMORY_SCOPE_AGENT);
}
__device__ __forceinline__ int flg_ld(const int* p) {
  return __hip_atomic_load(p, __ATOMIC_RELAXED, __HIP_MEMORY_SCOPE_AGENT);
}
__device__ __forceinline__ void flg_st(int* p, int v) {
  __hip_atomic_store(p, v, __ATOMIC_RELAXED, __HIP_MEMORY_SCOPE_AGENT);
}

// ---------------------------------------------------------------------------
// Weight pack: B-fragment order for mfma_f32_16x16x32_bf16 (verified R1-R10).
// ---------------------------------------------------------------------------
__global__ void pack_w_kernel(const float* __restrict__ W, short* __restrict__ out,
                              int Kin, int Ktiles) {
  int idx = blockIdx.x * 256 + threadIdx.x;
  int total = 64 * Ktiles * 64;
  if (idx >= total) return;
  int lane = idx & 63;
  int rest = idx >> 6;
  int ks   = rest % Ktiles;
  int tile = rest / Ktiles;
  int n  = tile * 16 + (lane & 15);
  int k0 = ks * 32 + (lane >> 4) * 8;
  short8 v;
#pragma unroll
  for (int j = 0; j < 8; ++j) {
    int k = k0 + j;
    float f = (k < Kin) ? W[(size_t)n * Kin + k] : 0.f;
    v[j] = (short)f2bf(f);
  }
  *(short8*)&out[(size_t)idx * 8] = v;
}

__global__ void bias_sum_kernel(const float* __restrict__ a, const float* __restrict__ b,
                                float* __restrict__ o) {
  int i = blockIdx.x * 256 + threadIdx.x;
  if (i < G4) o[i] = a[i] + b[i];
}

// ---------------------------------------------------------------------------
// Layer-0 gate GEMM (fp32 seq, K pad 40->64). Verified R6-R10. 1600 blocks.
// ---------------------------------------------------------------------------
__global__ __launch_bounds__(256, 2)
void gate_gemm0(const float* __restrict__ seq, const short* __restrict__ Wp,
                const float* __restrict__ bias, unsigned short* __restrict__ G) {
  const int btile = blockIdx.x % 40;
  const int rest  = blockIdx.x / 40;
  const int tg    = rest & 3;
  const int chunk = rest >> 2;
  const int tid = threadIdx.x, lane = tid & 63, wave = tid >> 6;
  const int nl = lane & 15, mq = lane >> 4;

  for (int mg = 0; mg < 4; ++mg) {
    const int t0 = chunk * 16 + mg * 4;
    f32x4 acc[4][4];
#pragma unroll
    for (int q = 0; q < 4; ++q) {
      int tile = tg * 16 + wave + 4 * q;
      float bv = bias[tile * 16 + nl];
#pragma unroll
      for (int mm = 0; mm < 4; ++mm) acc[mm][q] = (f32x4){bv, bv, bv, bv};
    }
    for (int kt = 0; kt < 2; ++kt) {
      short8 a[4];
      const int m = btile * 16 + nl;
      const int k0 = kt * 32 + mq * 8;
#pragma unroll
      for (int mm = 0; mm < 4; ++mm) {
#pragma unroll
        for (int j = 0; j < 8; ++j) {
          int k = k0 + j;
          float f = (k < IN_F) ? seq[((size_t)m * T_SEQ + (t0 + mm)) * IN_F + k] : 0.f;
          a[mm][j] = (short)f2bf(f);
        }
      }
#pragma unroll
      for (int q = 0; q < 4; ++q) {
        int tile = tg * 16 + wave + 4 * q;
        short8 b = *(const short8*)&Wp[(((size_t)tile * 2 + kt) * 64 + lane) * 8];
#pragma unroll
        for (int mm = 0; mm < 4; ++mm)
          acc[mm][q] = __builtin_amdgcn_mfma_f32_16x16x32_bf16(a[mm], b, acc[mm][q], 0, 0, 0);
      }
    }
#pragma unroll
    for (int mm = 0; mm < 4; ++mm)
#pragma unroll
      for (int q = 0; q < 4; ++q) {
        int tile = tg * 16 + wave + 4 * q;
        us4 o;
#pragma unroll
        for (int r = 0; r < 4; ++r) o[r] = f2bf(acc[mm][q][r]);
        *(us4*)&G[(((size_t)(t0 + mm) * 40 + btile) * 64 + tile) * 256 + lane * 4] = o;
      }
  }
}

// ---------------------------------------------------------------------------
// Fused 3-layer pipeline (R10 structure). R11 changes ONLY:
//  * flags padded to 256 B each + s_sleep backoff (kill flag-line contention)
//  * publish col-major DIRECTLY from hv registers, issued right after gates
//    (stores overlap h_sh update + barriers; one barrier removed)
// Slab word layout: w = col_local*16 + m*4 + mq  ->  rows m*16+mq*4+{0..3}
// of col. Consumers scatter 4 x u16 into row-major LDS.
// ---------------------------------------------------------------------------
template<int L>
__device__ __forceinline__ void rec_stage(
    int S, int hb,
    const short* __restrict__ Whhp, const short* __restrict__ Wihp,
    const unsigned short* __restrict__ G0, const float* __restrict__ biasl,
    unsigned long long* __restrict__ hxch, int* __restrict__ flags,
    const int* __restrict__ lens, float* __restrict__ c_state,
    unsigned short* h_sh, unsigned short* x_sh, float* c_sh,
    float* bias_sh, short* wih_lds, int* len_sh)
{
  const int tid = threadIdx.x, lane = tid & 63, wave = tid >> 6;
  const int mq = lane >> 4, nl = lane & 15;
  const int lc = wave * 16 + nl;
  const int colown = hb * 64 + lc;

  // Whh slice: 4 tiles x 8 kt = 32 frags (AGPR-parked, R6-R10 proven)
  short8 wregH[4][8];
#pragma unroll
  for (int g = 0; g < 4; ++g) {
    const int tile = g * 16 + hb * 4 + wave;
#pragma unroll
    for (int kt = 0; kt < 8; ++kt)
      wregH[g][kt] = *(const short8*)&Whhp[(((size_t)tile * 8 + kt) * 64 + lane) * 8];
  }
  // Wih slice (L>=1): kt 0..3 in regs (16 frags), kt 4..7 in LDS (64 KB)
  short8 wregI[4][4];
  if (L >= 1) {
#pragma unroll
    for (int g = 0; g < 4; ++g) {
      const int tile = g * 16 + hb * 4 + wave;
#pragma unroll
      for (int kt = 0; kt < 4; ++kt)
        wregI[g][kt] = *(const short8*)&Wihp[(((size_t)tile * 8 + kt) * 64 + lane) * 8];
    }
    for (int i = tid; i < 4096; i += 256) {
      int tl = i >> 6, ln = i & 63;
      int lt = tl >> 2, kt4 = tl & 3;
      int gt = (lt >> 2) * 16 + hb * 4 + (lt & 3);
      *(short8*)&wih_lds[(lt * 4 + kt4) * 512 + ln * 8] =
          *(const short8*)&Wihp[(((size_t)gt * 8 + 4 + kt4) * 64 + ln) * 8];
    }
    for (int i = tid; i < 1024; i += 256) bias_sh[i] = biasl[i];
  }
  for (int i = tid; i < 64 * 264; i += 256) h_sh[i] = 0;
  for (int i = tid; i < 64 * 65; i += 256) c_sh[i] = 0.f;
  if (tid < 64) len_sh[tid] = lens[S * 64 + tid];
  __syncthreads();

  const int fself = L * 40 + S * 4 + hb;

  for (int t = 0; t < T_SEQ; ++t) {
    const int par = t & 3;              // 4-deep parity
    // ---- waits (padded flags + sleep backoff) ----
    if (L >= 1 && tid < 4)
      while (flg_ld(&flags[((L - 1) * 40 + S * 4 + tid) * FSTR]) < t + 1)
        __builtin_amdgcn_s_sleep(1);
    if (L < 2 && tid >= 4 && tid < 8)
      while (flg_ld(&flags[((L + 1) * 40 + S * 4 + (tid - 4)) * FSTR]) < t - 3)
        __builtin_amdgcn_s_sleep(1);
    __syncthreads();                     // (A)

    // ---- issue x-pull early, BATCHED (latency hidden under Whh MFMAs) ----
    unsigned long long xr[16];
    if (L >= 1) {
      const unsigned long long* xb =
          hxch + ((size_t)((par * 3 + (L - 1)) * 10 + S)) * 4096;
#pragma unroll
      for (int u = 0; u < 16; ++u) xr[u] = ato_ld(&xb[u * 256 + tid]);
    }
    // ---- acc init: L==0 from G0 (bias folded), else bias ----
    f32x4 acc[4][4];
    if (L == 0) {
#pragma unroll
      for (int m = 0; m < 4; ++m)
#pragma unroll
        for (int g = 0; g < 4; ++g) {
          const int tile = g * 16 + hb * 4 + wave;
          us4 gv = *(const us4*)&G0[(((size_t)t * 40 + S * 4 + m) * 64 + tile) * 256 + lane * 4];
#pragma unroll
          for (int r = 0; r < 4; ++r) acc[m][g][r] = b2f(gv[r]);
        }
    } else {
#pragma unroll
      for (int g = 0; g < 4; ++g) {
        const int tile = g * 16 + hb * 4 + wave;
        float bv = bias_sh[tile * 16 + nl];
#pragma unroll
        for (int m = 0; m < 4; ++m) acc[m][g] = (f32x4){bv, bv, bv, bv};
      }
    }
    // ---- Whh MFMA over h[t-1] ----
#pragma unroll
    for (int kt = 0; kt < 8; ++kt) {
      short8 a[4];
#pragma unroll
      for (int m = 0; m < 4; ++m)
        a[m] = *(const short8*)&h_sh[(m * 16 + nl) * 264 + kt * 32 + mq * 8];
#pragma unroll
      for (int m = 0; m < 4; ++m)
#pragma unroll
        for (int g = 0; g < 4; ++g)
          acc[m][g] = __builtin_amdgcn_mfma_f32_16x16x32_bf16(a[m], wregH[g][kt], acc[m][g], 0, 0, 0);
    }
    // ---- x scatter -> LDS, then Wih MFMA ----
    if (L >= 1) {
#pragma unroll
      for (int u = 0; u < 16; ++u) {
        int j = u * 256 + tid, pp = j >> 10, jj = j & 1023;
        int col = pp * 64 + (jj >> 4);
        int row0 = ((jj & 15) >> 2) * 16 + (jj & 3) * 4;
        unsigned long long v = xr[u];
        x_sh[(row0 + 0) * 264 + col] = (unsigned short)v;
        x_sh[(row0 + 1) * 264 + col] = (unsigned short)(v >> 16);
        x_sh[(row0 + 2) * 264 + col] = (unsigned short)(v >> 32);
        x_sh[(row0 + 3) * 264 + col] = (unsigned short)(v >> 48);
      }
      __syncthreads();                   // (B)
#pragma unroll
      for (int kt = 0; kt < 8; ++kt) {
        short8 a[4];
#pragma unroll
        for (int m = 0; m < 4; ++m)
          a[m] = *(const short8*)&x_sh[(m * 16 + nl) * 264 + kt * 32 + mq * 8];
#pragma unroll
        for (int g = 0; g < 4; ++g) {
          short8 b = (kt < 4) ? wregI[g][kt]
                              : *(const short8*)&wih_lds[((g * 4 + wave) * 4 + (kt - 4)) * 512 + lane * 8];
#pragma unroll
          for (int m = 0; m < 4; ++m)
            acc[m][g] = __builtin_amdgcn_mfma_f32_16x16x32_bf16(a[m], b, acc[m][g], 0, 0, 0);
        }
      }
    }
    // ---- gates (C/D: row=m*16+mq*4+r, col=nl), c in LDS ----
    unsigned short hv[16];
#pragma unroll
    for (int m = 0; m < 4; ++m)
#pragma unroll
      for (int r = 0; r < 4; ++r) {
        const int row = m * 16 + mq * 4 + r;
        float c_old = c_sh[row * 65 + lc];
        float cn = sigm(acc[m][1][r]) * c_old + sigm(acc[m][0][r]) * tanh_fast(acc[m][2][r]);
        float hn = sigm(acc[m][3][r]) * tanh_fast(cn);
        bool upd = t < len_sh[row];
        if (upd) c_sh[row * 65 + lc] = cn;
        hv[m * 4 + r] = upd ? f2bf(hn) : h_sh[row * 264 + colown];
      }
    // ---- publish from regs (col-major words), overlaps LDS update ----
    {
      unsigned long long* myslab =
          hxch + ((size_t)((par * 3 + L) * 10 + S) * 4 + hb) * 1024;
#pragma unroll
      for (int m = 0; m < 4; ++m) {
        unsigned long long v =
            (unsigned long long)hv[m * 4 + 0] |
            ((unsigned long long)hv[m * 4 + 1] << 16) |
            ((unsigned long long)hv[m * 4 + 2] << 32) |
            ((unsigned long long)hv[m * 4 + 3] << 48);
        ato_st(&myslab[lc * 16 + m * 4 + mq], v);
      }
    }
    __syncthreads();                     // (1) all h_sh/x_sh reads done
#pragma unroll
    for (int m = 0; m < 4; ++m)
#pragma unroll
      for (int r = 0; r < 4; ++r)
        h_sh[(m * 16 + mq * 4 + r) * 264 + colown] = hv[m * 4 + r];
    __syncthreads();                     // (2) LDS visible + vmcnt drained
    if (tid == 0) flg_st(&flags[fself * FSTR], t + 1);
    if (tid < 3) {
      int p = tid + (tid >= hb ? 1 : 0);
      while (flg_ld(&flags[(L * 40 + S * 4 + p) * FSTR]) < t + 1)
        __builtin_amdgcn_s_sleep(1);
    }
    __syncthreads();                     // (4)
    // ---- pull 3 peer slabs, BATCHED, scatter to h_sh ----
    {
      unsigned long long pr[12];
#pragma unroll
      for (int u = 0; u < 12; ++u) {
        int j = u * 256 + tid;
        int pp = j >> 10, jj = j & 1023;
        int p = pp + (pp >= hb ? 1 : 0);
        pr[u] = ato_ld(&hxch[((size_t)((par * 3 + L) * 10 + S) * 4 + p) * 1024 + jj]);
      }
#pragma unroll
      for (int u = 0; u < 12; ++u) {
        int j = u * 256 + tid;
        int pp = j >> 10, jj = j & 1023;
        int p = pp + (pp >= hb ? 1 : 0);
        int col = p * 64 + (jj >> 4);
        int row0 = ((jj & 15) >> 2) * 16 + (jj & 3) * 4;
        unsigned long long v = pr[u];
        h_sh[(row0 + 0) * 264 + col] = (unsigned short)v;
        h_sh[(row0 + 1) * 264 + col] = (unsigned short)(v >> 16);
        h_sh[(row0 + 2) * 264 + col] = (unsigned short)(v >> 32);
        h_sh[(row0 + 3) * 264 + col] = (unsigned short)(v >> 48);
      }
    }
    __syncthreads();                     // (5) h[t] complete in LDS
  }
  if (L == 2) {
#pragma unroll
    for (int m = 0; m < 4; ++m)
#pragma unroll
      for (int r = 0; r < 4; ++r) {
        const int row = m * 16 + mq * 4 + r;
        c_state[((size_t)S * 64 + row) * 256 + colown] = c_sh[row * 65 + lc];
      }
  }
}

__global__ __launch_bounds__(256, 1)
void fused_lstm(const short* __restrict__ Whhp_all, const short* __restrict__ Wih1p,
                const short* __restrict__ Wih2p, const float* __restrict__ biasc,
                const unsigned short* __restrict__ G0, const int* __restrict__ lens,
                unsigned long long* __restrict__ hxch, int* __restrict__ flags,
                float* __restrict__ c_state)
{
  __shared__ unsigned short h_sh[64 * 264];   // 33792 B
  __shared__ unsigned short x_sh[64 * 264];   // 33792 B
  __shared__ float c_sh[64 * 65];             // 16640 B
  __shared__ float bias_sh[1024];             // 4096 B
  __shared__ short wih_lds[16 * 4 * 512];     // 65536 B   (total ~154 KB <= 160)
  __shared__ int len_sh[64];
  const int bid = blockIdx.x;                 // 0..119
  const int L = bid / 40;
  const int S = (bid % 40) >> 2;
  const int hb = bid & 3;

  if (L == 0)
    rec_stage<0>(S, hb, Whhp_all,          nullptr, G0, nullptr,
                 hxch, flags, lens, c_state, h_sh, x_sh, c_sh, bias_sh, wih_lds, len_sh);
  else if (L == 1)
    rec_stage<1>(S, hb, Whhp_all + 262144, Wih1p, G0, biasc + G4,
                 hxch, flags, lens, c_state, h_sh, x_sh, c_sh, bias_sh, wih_lds, len_sh);
  else
    rec_stage<2>(S, hb, Whhp_all + 524288, Wih2p, G0, biasc + 2 * G4,
                 hxch, flags, lens, c_state, h_sh, x_sh, c_sh, bias_sh, wih_lds, len_sh);
}

// ---------------------------------------------------------------------------
// Epilogue (verified R1-R10). E aliases c_state.
// ---------------------------------------------------------------------------
__global__ void k_norm(const float* __restrict__ E, float* __restrict__ E1,
                       float* __restrict__ En) {
  int row  = blockIdx.x * 4 + (threadIdx.x >> 6);
  int lane = threadIdx.x & 63;
  const float* e = E + (size_t)row * H_DIM;
  float v[4]; float ss = 0.f;
#pragma unroll
  for (int j = 0; j < 4; ++j) { v[j] = e[lane + 64 * j]; ss += v[j] * v[j]; }
#pragma unroll
  for (int m = 32; m >= 1; m >>= 1) ss += __shfl_xor(ss, m, 64);
  float nrm  = sqrtf(ss);
  float inv1 = 1.f / fmaxf(nrm, 1e-12f);
  float inv2 = 1.f / fmaxf(nrm * inv1, 1e-8f);
#pragma unroll
  for (int j = 0; j < 4; ++j) {
    float e1 = v[j] * inv1;
    E1[(size_t)row * H_DIM + lane + 64 * j] = e1;
    En[(size_t)row * H_DIM + lane + 64 * j] = e1 * inv2;
  }
}

__global__ void k_cent(const float* __restrict__ E1, float* __restrict__ C,
                       float* __restrict__ CnT) {
  int n = blockIdx.x;
  int lane = threadIdx.x;  // 64
  float v[4]; float ss = 0.f;
#pragma unroll
  for (int j = 0; j < 4; ++j) {
    int col = lane + 64 * j;
    float s = 0.f;
    for (int m = 0; m < M_UTT; ++m) s += E1[((size_t)n * M_UTT + m) * H_DIM + col];
    v[j] = s / (float)M_UTT;
    ss += v[j] * v[j];
  }
#pragma unroll
  for (int m = 32; m >= 1; m >>= 1) ss += __shfl_xor(ss, m, 64);
  float inv = 1.f / fmaxf(sqrtf(ss), 1e-8f);
#pragma unroll
  for (int j = 0; j < 4; ++j) {
    int col = lane + 64 * j;
    C[(size_t)n * H_DIM + col]  = v[j];
    CnT[(size_t)col * N_SPK + n] = v[j] * inv;
  }
}

__global__ void k_cm(const float* __restrict__ E1, const float* __restrict__ C,
                     float* __restrict__ Cmn) {
  int b    = blockIdx.x * 4 + (threadIdx.x >> 6);
  int lane = threadIdx.x & 63;
  int spk  = b / M_UTT;
  float v[4]; float ss = 0.f;
#pragma unroll
  for (int j = 0; j < 4; ++j) {
    int col = lane + 64 * j;
    v[j] = ((float)M_UTT * C[(size_t)spk * H_DIM + col] + E1[(size_t)b * H_DIM + col])
           / (float)(M_UTT - 1);
    ss += v[j] * v[j];
  }
#pragma unroll
  for (int m = 32; m >= 1; m >>= 1) ss += __shfl_xor(ss, m, 64);
  float inv = 1.f / fmaxf(sqrtf(ss), 1e-8f);
#pragma unroll
  for (int j = 0; j < 4; ++j)
    Cmn[(size_t)b * H_DIM + lane + 64 * j] = v[j] * inv;
}

__global__ void k_sim(const float* __restrict__ En, const float* __restrict__ CnT,
                      const float* __restrict__ Cmn, const float* __restrict__ w_sim,
                      const float* __restrict__ b_sim, float* __restrict__ S) {
  int b = blockIdx.x;
  int n = threadIdx.x;  // 64
  int diag = b / M_UTT;
  float w = w_sim[0], bb = b_sim[0];
  float s = 0.f;
  for (int k = 0; k < H_DIM; ++k) {
    float en = En[(size_t)b * H_DIM + k];
    float c  = (n == diag) ? Cmn[(size_t)b * H_DIM + k] : CnT[(size_t)k * N_SPK + n];
    s += en * c;
  }
  S[(size_t)b * N_SPK + n] = s * w + bb;
}

// ---------------------------------------------------------------------------
// Workspace layout (bytes). Total ~219 MB (R8's 222 MB proven available).
// ---------------------------------------------------------------------------
#define O_WHH   0ull            // 3 x 524288 = 1572864
#define O_WIH0  1572864ull      // 131072
#define O_WIH1  1703936ull      // 524288
#define O_WIH2  2228224ull      // 524288
#define O_BIAS  2752512ull      // 12288
#define O_CST   2764800ull      // 655360 (fp32 c of layer2 = E)
#define O_E1    3420160ull      // 655360
#define O_EN    4075520ull      // 655360
#define O_C     4730880ull      // 65536
#define O_CNT   4796416ull      // 65536
#define O_CMN   4861952ull      // 655360
#define O_FLG   5517312ull      // 30720 (120 flags x 256 B)
#define O_HXCH  5548032ull      // 3932160 (4par x 3l x 10S x 4hb x 8KB)
#define O_G0    9480192ull      // 209715200 -> end 219195392

extern "C" void kernel_launch(void* const* d_in, const int* in_sizes, int n_in,
                              void* d_out, int out_size, void* d_ws, size_t ws_size,
                              hipStream_t stream) {
  const float* seq   = (const float*)d_in[0];
  const int*   lens  = (const int*)d_in[1];
  const float* w_sim = (const float*)d_in[2];
  const float* b_sim = (const float*)d_in[3];
  const float* Wih[3] = {(const float*)d_in[4],  (const float*)d_in[8],  (const float*)d_in[12]};
  const float* Whh[3] = {(const float*)d_in[5],  (const float*)d_in[9],  (const float*)d_in[13]};
  const float* bih[3] = {(const float*)d_in[6],  (const float*)d_in[10], (const float*)d_in[14]};
  const float* bhh[3] = {(const float*)d_in[7],  (const float*)d_in[11], (const float*)d_in[15]};

  char* ws = (char*)d_ws;
  short* Whhp_all = (short*)(ws + O_WHH);
  short* Wihp[3] = {(short*)(ws + O_WIH0), (short*)(ws + O_WIH1), (short*)(ws + O_WIH2)};
  float* biasc = (float*)(ws + O_BIAS);
  float* c_state = (float*)(ws + O_CST);
  float* E1  = (float*)(ws + O_E1);
  float* En  = (float*)(ws + O_EN);
  float* C   = (float*)(ws + O_C);
  float* CnT = (float*)(ws + O_CNT);
  float* Cmn = (float*)(ws + O_CMN);
  int* flags = (int*)(ws + O_FLG);
  unsigned long long* hxch = (unsigned long long*)(ws + O_HXCH);
  unsigned short* G0 = (unsigned short*)(ws + O_G0);
  float* S = (float*)d_out;

  // ---- packs ----
  pack_w_kernel<<<32, 256, 0, stream>>>(Wih[0], Wihp[0], IN_F, 2);
  pack_w_kernel<<<128, 256, 0, stream>>>(Whh[0], Whhp_all, H_DIM, 8);
  pack_w_kernel<<<128, 256, 0, stream>>>(Whh[1], Whhp_all + 262144, H_DIM, 8);
  pack_w_kernel<<<128, 256, 0, stream>>>(Whh[2], Whhp_all + 524288, H_DIM, 8);
  pack_w_kernel<<<128, 256, 0, stream>>>(Wih[1], Wihp[1], H_DIM, 8);
  pack_w_kernel<<<128, 256, 0, stream>>>(Wih[2], Wihp[2], H_DIM, 8);
  for (int l = 0; l < 3; ++l)
    bias_sum_kernel<<<4, 256, 0, stream>>>(bih[l], bhh[l], biasc + l * G4);

  // ---- layer-0 gate GEMM (full T, bias folded) ----
  gate_gemm0<<<1600, 256, 0, stream>>>(seq, Wihp[0], biasc, G0);

  // ---- fused 3-layer pipeline (R-blocks only) ----
  hipMemsetAsync(ws + O_FLG, 0, 30720, stream);
  fused_lstm<<<120, 256, 0, stream>>>(Whhp_all, Wihp[1], Wihp[2], biasc, G0, lens,
                                      hxch, flags, c_state);

  // ---- similarity epilogue (E = c_state) ----
  k_norm<<<160, 256, 0, stream>>>(c_state, E1, En);
  k_cent<<<N_SPK, 64, 0, stream>>>(E1, C, CnT);
  k_cm<<<160, 256, 0, stream>>>(E1, C, Cmn);
  k_sim<<<B_TOT, 64, 0, stream>>>(En, CnT, Cmn, w_sim, b_sim, S);
}

// Round 12
// 1696.388 us; speedup vs baseline: 1.2551x; 1.2551x over previous
//
#include <hip/hip_runtime.h>
#include <cstdint>
#include <cstddef>

typedef __attribute__((ext_vector_type(8))) short short8;
typedef __attribute__((ext_vector_type(4))) float f32x4;
typedef __attribute__((ext_vector_type(4))) unsigned short us4;

#define N_SPK 64
#define M_UTT 10
#define T_SEQ 160
#define IN_F  40
#define H_DIM 256
#define B_TOT 640
#define G4    1024
#define FSTR  64   // flag stride in ints (256 B/flag: own cache line)

__device__ __forceinline__ unsigned short f2bf(float f) {
  unsigned int u = __float_as_uint(f);
  u += 0x7FFFu + ((u >> 16) & 1u);   // round-to-nearest-even
  return (unsigned short)(u >> 16);
}
__device__ __forceinline__ float b2f(unsigned short u) {
  return __uint_as_float(((unsigned int)u) << 16);
}
__device__ __forceinline__ float sigm(float x) {
  return 1.f / (1.f + __expf(-x));
}
__device__ __forceinline__ float tanh_fast(float x) {
  return 1.f - 2.f / (1.f + __expf(2.f * x));
}
__device__ __forceinline__ unsigned long long ato_ld(const unsigned long long* p) {
  return __hip_atomic_load(p, __ATOMIC_RELAXED, __HIP_MEMORY_SCOPE_AGENT);
}
__device__ __forceinline__ void ato_st(unsigned long long* p, unsigned long long v) {
  __hip_atomic_store(p, v, __ATOMIC_RELAXED, __HIP_MEMORY_SCOPE_AGENT);
}
__device__ __forceinline__ int flg_ld(const int* p) {
  return __hip_atomic_load(p, __ATOMIC_RELAXED, __HIP_MEMORY_SCOPE_AGENT);
}
__device__ __forceinline__ void flg_st(int* p, int v) {
  __hip_atomic_store(p, v, __ATOMIC_RELAXED, __HIP_MEMORY_SCOPE_AGENT);
}

// ---------------------------------------------------------------------------
// Weight pack: B-fragment order for mfma_f32_16x16x32_bf16 (verified R1-R11).
// ---------------------------------------------------------------------------
__global__ void pack_w_kernel(const float* __restrict__ W, short* __restrict__ out,
                              int Kin, int Ktiles) {
  int idx = blockIdx.x * 256 + threadIdx.x;
  int total = 64 * Ktiles * 64;
  if (idx >= total) return;
  int lane = idx & 63;
  int rest = idx >> 6;
  int ks   = rest % Ktiles;
  int tile = rest / Ktiles;
  int n  = tile * 16 + (lane & 15);
  int k0 = ks * 32 + (lane >> 4) * 8;
  short8 v;
#pragma unroll
  for (int j = 0; j < 8; ++j) {
    int k = k0 + j;
    float f = (k < Kin) ? W[(size_t)n * Kin + k] : 0.f;
    v[j] = (short)f2bf(f);
  }
  *(short8*)&out[(size_t)idx * 8] = v;
}

__global__ void bias_sum_kernel(const float* __restrict__ a, const float* __restrict__ b,
                                float* __restrict__ o) {
  int i = blockIdx.x * 256 + threadIdx.x;
  if (i < G4) o[i] = a[i] + b[i];
}

// ---------------------------------------------------------------------------
// Layer-0 gate GEMM (fp32 seq, K pad 40->64). Verified R6-R11. 1600 blocks.
// ---------------------------------------------------------------------------
__global__ __launch_bounds__(256, 2)
void gate_gemm0(const float* __restrict__ seq, const short* __restrict__ Wp,
                const float* __restrict__ bias, unsigned short* __restrict__ G) {
  const int btile = blockIdx.x % 40;
  const int rest  = blockIdx.x / 40;
  const int tg    = rest & 3;
  const int chunk = rest >> 2;
  const int tid = threadIdx.x, lane = tid & 63, wave = tid >> 6;
  const int nl = lane & 15, mq = lane >> 4;

  for (int mg = 0; mg < 4; ++mg) {
    const int t0 = chunk * 16 + mg * 4;
    f32x4 acc[4][4];
#pragma unroll
    for (int q = 0; q < 4; ++q) {
      int tile = tg * 16 + wave + 4 * q;
      float bv = bias[tile * 16 + nl];
#pragma unroll
      for (int mm = 0; mm < 4; ++mm) acc[mm][q] = (f32x4){bv, bv, bv, bv};
    }
    for (int kt = 0; kt < 2; ++kt) {
      short8 a[4];
      const int m = btile * 16 + nl;
      const int k0 = kt * 32 + mq * 8;
#pragma unroll
      for (int mm = 0; mm < 4; ++mm) {
#pragma unroll
        for (int j = 0; j < 8; ++j) {
          int k = k0 + j;
          float f = (k < IN_F) ? seq[((size_t)m * T_SEQ + (t0 + mm)) * IN_F + k] : 0.f;
          a[mm][j] = (short)f2bf(f);
        }
      }
#pragma unroll
      for (int q = 0; q < 4; ++q) {
        int tile = tg * 16 + wave + 4 * q;
        short8 b = *(const short8*)&Wp[(((size_t)tile * 2 + kt) * 64 + lane) * 8];
#pragma unroll
        for (int mm = 0; mm < 4; ++mm)
          acc[mm][q] = __builtin_amdgcn_mfma_f32_16x16x32_bf16(a[mm], b, acc[mm][q], 0, 0, 0);
      }
    }
#pragma unroll
    for (int mm = 0; mm < 4; ++mm)
#pragma unroll
      for (int q = 0; q < 4; ++q) {
        int tile = tg * 16 + wave + 4 * q;
        us4 o;
#pragma unroll
        for (int r = 0; r < 4; ++r) o[r] = f2bf(acc[mm][q][r]);
        *(us4*)&G[(((size_t)(t0 + mm) * 40 + btile) * 64 + tile) * 256 + lane * 4] = o;
      }
  }
}

// ---------------------------------------------------------------------------
// Fused 3-layer pipeline. R12 = R10 structure (proven best) + padded flags
// (no sleep) + L0 G0 double-buffered prefetch via x_sh (the R7 trick every
// fused version dropped): G0[t+1] is staged into x_sh (unused by L0) in the
// shadow of the peer-poll window, so the pace-setting L0 stage no longer
// pays serialized HBM latency at step start. R11's col-major publish and
// u16 scatters are REVERTED (5.8x LDS bank conflicts).
// ---------------------------------------------------------------------------
template<int L>
__device__ __forceinline__ void rec_stage(
    int S, int hb,
    const short* __restrict__ Whhp, const short* __restrict__ Wihp,
    const unsigned short* __restrict__ G0, const float* __restrict__ biasl,
    unsigned long long* __restrict__ hxch, int* __restrict__ flags,
    const int* __restrict__ lens, float* __restrict__ c_state,
    unsigned short* h_sh, unsigned short* x_sh, float* c_sh,
    float* bias_sh, short* wih_lds, int* len_sh)
{
  const int tid = threadIdx.x, lane = tid & 63, wave = tid >> 6;
  const int mq = lane >> 4, nl = lane & 15;
  const int lc = wave * 16 + nl;
  const int colown = hb * 64 + lc;
  unsigned long long* x64 = (unsigned long long*)x_sh;

  // Whh slice: 4 tiles x 8 kt = 32 frags (AGPR-parked, R6-R11 proven)
  short8 wregH[4][8];
#pragma unroll
  for (int g = 0; g < 4; ++g) {
    const int tile = g * 16 + hb * 4 + wave;
#pragma unroll
    for (int kt = 0; kt < 8; ++kt)
      wregH[g][kt] = *(const short8*)&Whhp[(((size_t)tile * 8 + kt) * 64 + lane) * 8];
  }
  // Wih slice (L>=1): kt 0..3 in regs (16 frags), kt 4..7 in LDS (64 KB)
  short8 wregI[4][4];
  if (L >= 1) {
#pragma unroll
    for (int g = 0; g < 4; ++g) {
      const int tile = g * 16 + hb * 4 + wave;
#pragma unroll
      for (int kt = 0; kt < 4; ++kt)
        wregI[g][kt] = *(const short8*)&Wihp[(((size_t)tile * 8 + kt) * 64 + lane) * 8];
    }
    for (int i = tid; i < 4096; i += 256) {
      int tl = i >> 6, ln = i & 63;
      int lt = tl >> 2, kt4 = tl & 3;
      int gt = (lt >> 2) * 16 + hb * 4 + (lt & 3);
      *(short8*)&wih_lds[(lt * 4 + kt4) * 512 + ln * 8] =
          *(const short8*)&Wihp[(((size_t)gt * 8 + 4 + kt4) * 64 + ln) * 8];
    }
    for (int i = tid; i < 1024; i += 256) bias_sh[i] = biasl[i];
  }
  for (int i = tid; i < 64 * 264; i += 256) h_sh[i] = 0;
  for (int i = tid; i < 64 * 65; i += 256) c_sh[i] = 0.f;
  if (tid < 64) len_sh[tid] = lens[S * 64 + tid];

  // L0: stage G0[0] into x_sh (thread-private 8B slots, conflict-free)
  if (L == 0) {
    us4 tmp[16];
#pragma unroll
    for (int m = 0; m < 4; ++m)
#pragma unroll
      for (int g = 0; g < 4; ++g) {
        const int tile = g * 16 + hb * 4 + wave;
        tmp[m * 4 + g] = *(const us4*)&G0[(((size_t)0 * 40 + S * 4 + m) * 64 + tile) * 256 + lane * 4];
      }
#pragma unroll
    for (int u = 0; u < 16; ++u)
      x64[u * 256 + tid] = *(unsigned long long*)&tmp[u];
  }
  __syncthreads();

  const int fself = L * 40 + S * 4 + hb;

  for (int t = 0; t < T_SEQ; ++t) {
    const int par = t & 3;              // 4-deep parity
    // ---- waits (padded flags, no sleep) ----
    if (L >= 1 && tid < 4)
      while (flg_ld(&flags[((L - 1) * 40 + S * 4 + tid) * FSTR]) < t + 1) {}
    if (L < 2 && tid >= 4 && tid < 8)
      while (flg_ld(&flags[((L + 1) * 40 + S * 4 + (tid - 4)) * FSTR]) < t - 3) {}
    __syncthreads();                     // (A)

    // ---- issue x-pull early, BATCHED (latency hidden under Whh MFMAs) ----
    unsigned long long xr[16];
    if (L >= 1) {
      const unsigned long long* xb =
          hxch + ((size_t)((par * 3 + (L - 1)) * 10 + S)) * 4096;
#pragma unroll
      for (int u = 0; u < 16; ++u) xr[u] = ato_ld(&xb[u * 256 + tid]);
    }
    // ---- acc init: L==0 from staged G0 (LDS), else bias ----
    f32x4 acc[4][4];
    if (L == 0) {
#pragma unroll
      for (int m = 0; m < 4; ++m)
#pragma unroll
        for (int g = 0; g < 4; ++g) {
          unsigned long long v = x64[(m * 4 + g) * 256 + tid];
          us4 gv = *(us4*)&v;
#pragma unroll
          for (int r = 0; r < 4; ++r) acc[m][g][r] = b2f(gv[r]);
        }
    } else {
#pragma unroll
      for (int g = 0; g < 4; ++g) {
        const int tile = g * 16 + hb * 4 + wave;
        float bv = bias_sh[tile * 16 + nl];
#pragma unroll
        for (int m = 0; m < 4; ++m) acc[m][g] = (f32x4){bv, bv, bv, bv};
      }
    }
    // ---- Whh MFMA over h[t-1] ----
#pragma unroll
    for (int kt = 0; kt < 8; ++kt) {
      short8 a[4];
#pragma unroll
      for (int m = 0; m < 4; ++m)
        a[m] = *(const short8*)&h_sh[(m * 16 + nl) * 264 + kt * 32 + mq * 8];
#pragma unroll
      for (int m = 0; m < 4; ++m)
#pragma unroll
        for (int g = 0; g < 4; ++g)
          acc[m][g] = __builtin_amdgcn_mfma_f32_16x16x32_bf16(a[m], wregH[g][kt], acc[m][g], 0, 0, 0);
    }
    // ---- x -> LDS (8B row-major stores, R10 form), then Wih MFMA ----
    if (L >= 1) {
#pragma unroll
      for (int u = 0; u < 16; ++u) {
        int j = u * 256 + tid, pp = j >> 10, jj = j & 1023;
        *(unsigned long long*)&x_sh[(jj >> 4) * 264 + pp * 64 + (jj & 15) * 4] = xr[u];
      }
      __syncthreads();                   // (B)
#pragma unroll
      for (int kt = 0; kt < 8; ++kt) {
        short8 a[4];
#pragma unroll
        for (int m = 0; m < 4; ++m)
          a[m] = *(const short8*)&x_sh[(m * 16 + nl) * 264 + kt * 32 + mq * 8];
#pragma unroll
        for (int g = 0; g < 4; ++g) {
          short8 b = (kt < 4) ? wregI[g][kt]
                              : *(const short8*)&wih_lds[((g * 4 + wave) * 4 + (kt - 4)) * 512 + lane * 8];
#pragma unroll
          for (int m = 0; m < 4; ++m)
            acc[m][g] = __builtin_amdgcn_mfma_f32_16x16x32_bf16(a[m], b, acc[m][g], 0, 0, 0);
        }
      }
    }
    // ---- gates (C/D: row=m*16+mq*4+r, col=nl), c in LDS ----
    unsigned short hv[16];
#pragma unroll
    for (int m = 0; m < 4; ++m)
#pragma unroll
      for (int r = 0; r < 4; ++r) {
        const int row = m * 16 + mq * 4 + r;
        float c_old = c_sh[row * 65 + lc];
        float cn = sigm(acc[m][1][r]) * c_old + sigm(acc[m][0][r]) * tanh_fast(acc[m][2][r]);
        float hn = sigm(acc[m][3][r]) * tanh_fast(cn);
        bool upd = t < len_sh[row];
        if (upd) c_sh[row * 65 + lc] = cn;
        hv[m * 4 + r] = upd ? f2bf(hn) : h_sh[row * 264 + colown];
      }
    __syncthreads();                     // (1) all h_sh/x_sh reads done
#pragma unroll
    for (int m = 0; m < 4; ++m)
#pragma unroll
      for (int r = 0; r < 4; ++r)
        h_sh[(m * 16 + mq * 4 + r) * 264 + colown] = hv[m * 4 + r];
    __syncthreads();                     // (2) own cols in LDS
    // ---- publish own 8 KB slab (R10 form: coalesced from LDS) ----
    unsigned long long* myslab =
        hxch + ((size_t)((par * 3 + L) * 10 + S) * 4 + hb) * 1024;
    for (int j = tid; j < 1024; j += 256) {
      int sample = j >> 4, l4 = j & 15;
      unsigned long long v =
          *(const unsigned long long*)&h_sh[sample * 264 + hb * 64 + l4 * 4];
      ato_st(&myslab[j], v);
    }
    __syncthreads();                     // (3) stores drained (vmcnt0)
    if (tid == 0) flg_st(&flags[fself * FSTR], t + 1);
    // ---- L0: prefetch G0[t+1] into x_sh in the poll/pull shadow ----
    if (L == 0) {
      int tn = (t + 1 < T_SEQ) ? t + 1 : t;
      us4 tmp[16];
#pragma unroll
      for (int m = 0; m < 4; ++m)
#pragma unroll
        for (int g = 0; g < 4; ++g) {
          const int tile = g * 16 + hb * 4 + wave;
          tmp[m * 4 + g] = *(const us4*)&G0[(((size_t)tn * 40 + S * 4 + m) * 64 + tile) * 256 + lane * 4];
        }
#pragma unroll
      for (int u = 0; u < 16; ++u)
        x64[u * 256 + tid] = *(unsigned long long*)&tmp[u];
    }
    if (tid < 3) {
      int p = tid + (tid >= hb ? 1 : 0);
      while (flg_ld(&flags[(L * 40 + S * 4 + p) * FSTR]) < t + 1) {}
    }
    __syncthreads();                     // (4)
    // ---- pull 3 peer slabs, BATCHED (R10 form: 8B row-major scatter) ----
    {
      unsigned long long pr[12];
#pragma unroll
      for (int u = 0; u < 12; ++u) {
        int j = u * 256 + tid;
        int pp = j >> 10, jj = j & 1023;
        int p = pp + (pp >= hb ? 1 : 0);
        pr[u] = ato_ld(&hxch[((size_t)((par * 3 + L) * 10 + S) * 4 + p) * 1024 + jj]);
      }
#pragma unroll
      for (int u = 0; u < 12; ++u) {
        int j = u * 256 + tid;
        int pp = j >> 10, jj = j & 1023;
        int p = pp + (pp >= hb ? 1 : 0);
        *(unsigned long long*)&h_sh[(jj >> 4) * 264 + p * 64 + (jj & 15) * 4] = pr[u];
      }
    }
    __syncthreads();                     // (5) h[t] complete in LDS
  }
  if (L == 2) {
#pragma unroll
    for (int m = 0; m < 4; ++m)
#pragma unroll
      for (int r = 0; r < 4; ++r) {
        const int row = m * 16 + mq * 4 + r;
        c_state[((size_t)S * 64 + row) * 256 + colown] = c_sh[row * 65 + lc];
      }
  }
}

__global__ __launch_bounds__(256, 1)
void fused_lstm(const short* __restrict__ Whhp_all, const short* __restrict__ Wih1p,
                const short* __restrict__ Wih2p, const float* __restrict__ biasc,
                const unsigned short* __restrict__ G0, const int* __restrict__ lens,
                unsigned long long* __restrict__ hxch, int* __restrict__ flags,
                float* __restrict__ c_state)
{
  __shared__ unsigned short h_sh[64 * 264];   // 33792 B
  __shared__ unsigned short x_sh[64 * 264];   // 33792 B (L0: G0 staging)
  __shared__ float c_sh[64 * 65];             // 16640 B
  __shared__ float bias_sh[1024];             // 4096 B
  __shared__ short wih_lds[16 * 4 * 512];     // 65536 B   (total ~154 KB <= 160)
  __shared__ int len_sh[64];
  const int bid = blockIdx.x;                 // 0..119
  const int L = bid / 40;
  const int S = (bid % 40) >> 2;
  const int hb = bid & 3;

  if (L == 0)
    rec_stage<0>(S, hb, Whhp_all,          nullptr, G0, nullptr,
                 hxch, flags, lens, c_state, h_sh, x_sh, c_sh, bias_sh, wih_lds, len_sh);
  else if (L == 1)
    rec_stage<1>(S, hb, Whhp_all + 262144, Wih1p, G0, biasc + G4,
                 hxch, flags, lens, c_state, h_sh, x_sh, c_sh, bias_sh, wih_lds, len_sh);
  else
    rec_stage<2>(S, hb, Whhp_all + 524288, Wih2p, G0, biasc + 2 * G4,
                 hxch, flags, lens, c_state, h_sh, x_sh, c_sh, bias_sh, wih_lds, len_sh);
}

// ---------------------------------------------------------------------------
// Epilogue (verified R1-R11). E aliases c_state.
// ---------------------------------------------------------------------------
__global__ void k_norm(const float* __restrict__ E, float* __restrict__ E1,
                       float* __restrict__ En) {
  int row  = blockIdx.x * 4 + (threadIdx.x >> 6);
  int lane = threadIdx.x & 63;
  const float* e = E + (size_t)row * H_DIM;
  float v[4]; float ss = 0.f;
#pragma unroll
  for (int j = 0; j < 4; ++j) { v[j] = e[lane + 64 * j]; ss += v[j] * v[j]; }
#pragma unroll
  for (int m = 32; m >= 1; m >>= 1) ss += __shfl_xor(ss, m, 64);
  float nrm  = sqrtf(ss);
  float inv1 = 1.f / fmaxf(nrm, 1e-12f);
  float inv2 = 1.f / fmaxf(nrm * inv1, 1e-8f);
#pragma unroll
  for (int j = 0; j < 4; ++j) {
    float e1 = v[j] * inv1;
    E1[(size_t)row * H_DIM + lane + 64 * j] = e1;
    En[(size_t)row * H_DIM + lane + 64 * j] = e1 * inv2;
  }
}

__global__ void k_cent(const float* __restrict__ E1, float* __restrict__ C,
                       float* __restrict__ CnT) {
  int n = blockIdx.x;
  int lane = threadIdx.x;  // 64
  float v[4]; float ss = 0.f;
#pragma unroll
  for (int j = 0; j < 4; ++j) {
    int col = lane + 64 * j;
    float s = 0.f;
    for (int m = 0; m < M_UTT; ++m) s += E1[((size_t)n * M_UTT + m) * H_DIM + col];
    v[j] = s / (float)M_UTT;
    ss += v[j] * v[j];
  }
#pragma unroll
  for (int m = 32; m >= 1; m >>= 1) ss += __shfl_xor(ss, m, 64);
  float inv = 1.f / fmaxf(sqrtf(ss), 1e-8f);
#pragma unroll
  for (int j = 0; j < 4; ++j) {
    int col = lane + 64 * j;
    C[(size_t)n * H_DIM + col]  = v[j];
    CnT[(size_t)col * N_SPK + n] = v[j] * inv;
  }
}

__global__ void k_cm(const float* __restrict__ E1, const float* __restrict__ C,
                     float* __restrict__ Cmn) {
  int b    = blockIdx.x * 4 + (threadIdx.x >> 6);
  int lane = threadIdx.x & 63;
  int spk  = b / M_UTT;
  float v[4]; float ss = 0.f;
#pragma unroll
  for (int j = 0; j < 4; ++j) {
    int col = lane + 64 * j;
    v[j] = ((float)M_UTT * C[(size_t)spk * H_DIM + col] + E1[(size_t)b * H_DIM + col])
           / (float)(M_UTT - 1);
    ss += v[j] * v[j];
  }
#pragma unroll
  for (int m = 32; m >= 1; m >>= 1) ss += __shfl_xor(ss, m, 64);
  float inv = 1.f / fmaxf(sqrtf(ss), 1e-8f);
#pragma unroll
  for (int j = 0; j < 4; ++j)
    Cmn[(size_t)b * H_DIM + lane + 64 * j] = v[j] * inv;
}

__global__ void k_sim(const float* __restrict__ En, const float* __restrict__ CnT,
                      const float* __restrict__ Cmn, const float* __restrict__ w_sim,
                      const float* __restrict__ b_sim, float* __restrict__ S) {
  int b = blockIdx.x;
  int n = threadIdx.x;  // 64
  int diag = b / M_UTT;
  float w = w_sim[0], bb = b_sim[0];
  float s = 0.f;
  for (int k = 0; k < H_DIM; ++k) {
    float en = En[(size_t)b * H_DIM + k];
    float c  = (n == diag) ? Cmn[(size_t)b * H_DIM + k] : CnT[(size_t)k * N_SPK + n];
    s += en * c;
  }
  S[(size_t)b * N_SPK + n] = s * w + bb;
}

// ---------------------------------------------------------------------------
// Workspace layout (bytes). Total ~219 MB (proven available).
// ---------------------------------------------------------------------------
#define O_WHH   0ull            // 3 x 524288 = 1572864
#define O_WIH0  1572864ull      // 131072
#define O_WIH1  1703936ull      // 524288
#define O_WIH2  2228224ull      // 524288
#define O_BIAS  2752512ull      // 12288
#define O_CST   2764800ull      // 655360 (fp32 c of layer2 = E)
#define O_E1    3420160ull      // 655360
#define O_EN    4075520ull      // 655360
#define O_C     4730880ull      // 65536
#define O_CNT   4796416ull      // 65536
#define O_CMN   4861952ull      // 655360
#define O_FLG   5517312ull      // 30720 (120 flags x 256 B)
#define O_HXCH  5548032ull      // 3932160 (4par x 3l x 10S x 4hb x 8KB)
#define O_G0    9480192ull      // 209715200 -> end 219195392

extern "C" void kernel_launch(void* const* d_in, const int* in_sizes, int n_in,
                              void* d_out, int out_size, void* d_ws, size_t ws_size,
                              hipStream_t stream) {
  const float* seq   = (const float*)d_in[0];
  const int*   lens  = (const int*)d_in[1];
  const float* w_sim = (const float*)d_in[2];
  const float* b_sim = (const float*)d_in[3];
  const float* Wih[3] = {(const float*)d_in[4],  (const float*)d_in[8],  (const float*)d_in[12]};
  const float* Whh[3] = {(const float*)d_in[5],  (const float*)d_in[9],  (const float*)d_in[13]};
  const float* bih[3] = {(const float*)d_in[6],  (const float*)d_in[10], (const float*)d_in[14]};
  const float* bhh[3] = {(const float*)d_in[7],  (const float*)d_in[11], (const float*)d_in[15]};

  char* ws = (char*)d_ws;
  short* Whhp_all = (short*)(ws + O_WHH);
  short* Wihp[3] = {(short*)(ws + O_WIH0), (short*)(ws + O_WIH1), (short*)(ws + O_WIH2)};
  float* biasc = (float*)(ws + O_BIAS);
  float* c_state = (float*)(ws + O_CST);
  float* E1  = (float*)(ws + O_E1);
  float* En  = (float*)(ws + O_EN);
  float* C   = (float*)(ws + O_C);
  float* CnT = (float*)(ws + O_CNT);
  float* Cmn = (float*)(ws + O_CMN);
  int* flags = (int*)(ws + O_FLG);
  unsigned long long* hxch = (unsigned long long*)(ws + O_HXCH);
  unsigned short* G0 = (unsigned short*)(ws + O_G0);
  float* S = (float*)d_out;

  // ---- packs ----
  pack_w_kernel<<<32, 256, 0, stream>>>(Wih[0], Wihp[0], IN_F, 2);
  pack_w_kernel<<<128, 256, 0, stream>>>(Whh[0], Whhp_all, H_DIM, 8);
  pack_w_kernel<<<128, 256, 0, stream>>>(Whh[1], Whhp_all + 262144, H_DIM, 8);
  pack_w_kernel<<<128, 256, 0, stream>>>(Whh[2], Whhp_all + 524288, H_DIM, 8);
  pack_w_kernel<<<128, 256, 0, stream>>>(Wih[1], Wihp[1], H_DIM, 8);
  pack_w_kernel<<<128, 256, 0, stream>>>(Wih[2], Wihp[2], H_DIM, 8);
  for (int l = 0; l < 3; ++l)
    bias_sum_kernel<<<4, 256, 0, stream>>>(bih[l], bhh[l], biasc + l * G4);

  // ---- layer-0 gate GEMM (full T, bias folded) ----
  gate_gemm0<<<1600, 256, 0, stream>>>(seq, Wihp[0], biasc, G0);

  // ---- fused 3-layer pipeline (R-blocks only) ----
  hipMemsetAsync(ws + O_FLG, 0, 30720, stream);
  fused_lstm<<<120, 256, 0, stream>>>(Whhp_all, Wihp[1], Wihp[2], biasc, G0, lens,
                                      hxch, flags, c_state);

  // ---- similarity epilogue (E = c_state) ----
  k_norm<<<160, 256, 0, stream>>>(c_state, E1, En);
  k_cent<<<N_SPK, 64, 0, stream>>>(E1, C, CnT);
  k_cm<<<160, 256, 0, stream>>>(E1, C, Cmn);
  k_sim<<<B_TOT, 64, 0, stream>>>(En, CnT, Cmn, w_sim, b_sim, S);
}